// Round 1
// baseline (1441.416 us; speedup 1.0000x reference)
//
#include <hip/hip_runtime.h>
#include <math.h>

#define EMB 64
#define HEADS 4
#define HC 256
#define EDGE_DIM 16
#define NEG_SLOPE 0.2f
#define LN_EPS 1e-5f

__device__ __forceinline__ void atomicMaxF(float* addr, float v) {
    if (v >= 0.0f) atomicMax((int*)addr, __float_as_int(v));
    else atomicMin((unsigned int*)addr, __float_as_uint(v));
}

// init: amax=-inf; node_ae_sum=0; denom=0; cnt=0
__global__ void k_init(float* amax, float* node_ae_sum, float* denom, float* cnt, int n) {
    int i = blockIdx.x * blockDim.x + threadIdx.x;
    if (i < n * HEADS) {
        amax[i] = -INFINITY;
        node_ae_sum[i] = 0.0f;
        denom[i] = 0.0f;
    }
    if (i < n) cnt[i] = 0.0f;
}

// we_att[d,h] = sum_c W_edge[d, h*64+c] * att_edge[h,c]   (16x4)
__global__ void k_we_att(const float* __restrict__ W_edge, const float* __restrict__ att_edge,
                         float* __restrict__ we_att) {
    int tid = threadIdx.x; // 64 threads
    int d = tid >> 2, h = tid & 3;
    float acc = 0.0f;
#pragma unroll
    for (int c = 0; c < EMB; ++c)
        acc += W_edge[d * HC + h * EMB + c] * att_edge[h * EMB + c];
    we_att[d * HEADS + h] = acc;
}

// xw = x @ W  (block per node, 256 threads); fused a_src/a_dst per-head reductions
__global__ void k_node_transform(const float* __restrict__ x, const float* __restrict__ W,
                                 const float* __restrict__ att_src, const float* __restrict__ att_dst,
                                 float* __restrict__ xw, float* __restrict__ a_src,
                                 float* __restrict__ a_dst) {
    int node = blockIdx.x;
    int tid = threadIdx.x;
    __shared__ float xs[EMB];
    if (tid < EMB) xs[tid] = x[node * EMB + tid];
    __syncthreads();
    float acc = 0.0f;
#pragma unroll
    for (int k = 0; k < EMB; ++k) acc += xs[k] * W[k * HC + tid];
    xw[(size_t)node * HC + tid] = acc;
    int h = tid >> 6, c = tid & 63;
    float vs = acc * att_src[tid];   // att_src flat [h*64+c] == tid
    float vd = acc * att_dst[tid];
    for (int off = 32; off > 0; off >>= 1) {
        vs += __shfl_down(vs, off);
        vd += __shfl_down(vd, off);
    }
    if (c == 0) { a_src[node * HEADS + h] = vs; a_dst[node * HEADS + h] = vd; }
}

// edge pass 1: a_edge, alpha(leaky), atomic max per dst, atomic sums for loop attr
__global__ void k_edge1(const int* __restrict__ ei, const float* __restrict__ edge_attr,
                        const float* __restrict__ we_att, const float* __restrict__ a_src,
                        const float* __restrict__ a_dst, float* __restrict__ alphabuf,
                        float* __restrict__ amax, float* __restrict__ node_ae_sum,
                        float* __restrict__ cnt, int E) {
    __shared__ float wa[EDGE_DIM * HEADS];
    if (threadIdx.x < EDGE_DIM * HEADS) wa[threadIdx.x] = we_att[threadIdx.x];
    __syncthreads();
    int e = blockIdx.x * blockDim.x + threadIdx.x;
    if (e >= E) return;
    int s = ei[e], d = ei[E + e];
    const float4* ea4 = (const float4*)(edge_attr + (size_t)e * EDGE_DIM);
    float ae[HEADS] = {0.f, 0.f, 0.f, 0.f};
#pragma unroll
    for (int q = 0; q < 4; ++q) {
        float4 v4 = ea4[q];
        const float* vp = (const float*)&v4;
#pragma unroll
        for (int r = 0; r < 4; ++r) {
            int dd = q * 4 + r;
            float v = vp[r];
#pragma unroll
            for (int h = 0; h < HEADS; ++h) ae[h] += v * wa[dd * HEADS + h];
        }
    }
    atomicAdd(&cnt[d], 1.0f);
    float4 al4;
    float* alp = (float*)&al4;
#pragma unroll
    for (int h = 0; h < HEADS; ++h) {
        atomicAdd(&node_ae_sum[d * HEADS + h], ae[h]);
        float al = a_src[s * HEADS + h] + a_dst[d * HEADS + h] + ae[h];
        al = al >= 0.0f ? al : NEG_SLOPE * al;
        alp[h] = al;
        atomicMaxF(&amax[d * HEADS + h], al);
    }
    *(float4*)(alphabuf + (size_t)e * HEADS) = al4;
}

// per-node self loop alpha; fold into amax
__global__ void k_node_loop(const float* __restrict__ a_src, const float* __restrict__ a_dst,
                            const float* __restrict__ node_ae_sum, const float* __restrict__ cnt,
                            float* __restrict__ amax, float* __restrict__ alpha_loop, int n) {
    int i = blockIdx.x * blockDim.x + threadIdx.x;
    if (i >= n * HEADS) return;
    int node = i >> 2;
    float ael = node_ae_sum[i] / fmaxf(cnt[node], 1.0f);
    float al = a_src[i] + a_dst[i] + ael;
    al = al >= 0.0f ? al : NEG_SLOPE * al;
    alpha_loop[i] = al;
    amax[i] = fmaxf(amax[i], al);
}

// edge pass 2: exp(alpha - amax[dst]); atomic denom
__global__ void k_edge2(const int* __restrict__ ei, float* __restrict__ alphabuf,
                        const float* __restrict__ amax, float* __restrict__ denom, int E) {
    int e = blockIdx.x * blockDim.x + threadIdx.x;
    if (e >= E) return;
    int d = ei[E + e];
    float4 al4 = *(float4*)(alphabuf + (size_t)e * HEADS);
    float* alp = (float*)&al4;
#pragma unroll
    for (int h = 0; h < HEADS; ++h) {
        float ex = __expf(alp[h] - amax[d * HEADS + h]);
        alp[h] = ex;
        atomicAdd(&denom[d * HEADS + h], ex);
    }
    *(float4*)(alphabuf + (size_t)e * HEADS) = al4;
}

// node pass: fold loop into denom; init agg with loop message
__global__ void k_node_agg_init(const float* __restrict__ alpha_loop, const float* __restrict__ amax,
                                float* __restrict__ denom, const float* __restrict__ xw,
                                float* __restrict__ agg) {
    int node = blockIdx.x;
    int tid = threadIdx.x;
    __shared__ float attn_l[HEADS];
    if (tid < HEADS) {
        int i = node * HEADS + tid;
        float el = __expf(alpha_loop[i] - amax[i]);
        float dn = denom[i] + el;
        denom[i] = dn;
        attn_l[tid] = el / dn;
    }
    __syncthreads();
    int h = tid >> 6;
    agg[(size_t)node * HC + tid] = attn_l[h] * xw[(size_t)node * HC + tid];
}

// edge pass 3: scatter attn * xw[src] into agg[dst] (block per edge)
__global__ void k_edge3(const int* __restrict__ ei, const float* __restrict__ alphabuf,
                        const float* __restrict__ denom, const float* __restrict__ xw,
                        float* __restrict__ agg, int E) {
    int e = blockIdx.x;
    int tid = threadIdx.x;
    __shared__ int sd[2];
    __shared__ float at[HEADS];
    if (tid == 0) { sd[0] = ei[e]; sd[1] = ei[E + e]; }
    __syncthreads();
    if (tid < HEADS) at[tid] = alphabuf[(size_t)e * HEADS + tid] / denom[sd[1] * HEADS + tid];
    __syncthreads();
    int h = tid >> 6;
    float v = at[h] * xw[(size_t)sd[0] * HC + tid];
    atomicAdd(&agg[(size_t)sd[1] * HC + tid], v);
}

// epilogue: +bias -> @Wp -> +bp -> elu -> residual -> LayerNorm
__global__ void k_out(const float* __restrict__ x, const float* __restrict__ agg,
                      const float* __restrict__ bias, const float* __restrict__ Wp,
                      const float* __restrict__ bp, const float* __restrict__ gamma,
                      const float* __restrict__ beta, float* __restrict__ out) {
    int node = blockIdx.x;
    int tid = threadIdx.x;
    __shared__ float g[HC];
    __shared__ float ps[HC];
    g[tid] = agg[(size_t)node * HC + tid] + bias[tid];
    __syncthreads();
    int k = tid & 63, part = tid >> 6;
    float acc = 0.0f;
#pragma unroll
    for (int j = 0; j < 64; ++j) {
        int jj = part * 64 + j;
        acc += g[jj] * Wp[jj * EMB + k];
    }
    ps[tid] = acc;
    __syncthreads();
    if (tid < EMB) {
        float p = ps[k] + ps[64 + k] + ps[128 + k] + ps[192 + k] + bp[k];
        float el = p > 0.0f ? p : expm1f(p);
        float hv = x[(size_t)node * EMB + k] + el;
        float s1 = hv, s2 = hv * hv;
        for (int off = 32; off > 0; off >>= 1) {
            s1 += __shfl_xor(s1, off);
            s2 += __shfl_xor(s2, off);
        }
        float mu = s1 * (1.0f / EMB);
        float var = s2 * (1.0f / EMB) - mu * mu;
        out[(size_t)node * EMB + k] = (hv - mu) * rsqrtf(var + LN_EPS) * gamma[k] + beta[k];
    }
}

extern "C" void kernel_launch(void* const* d_in, const int* in_sizes, int n_in,
                              void* d_out, int out_size, void* d_ws, size_t ws_size,
                              hipStream_t stream) {
    const float* x        = (const float*)d_in[0];
    const int*   ei       = (const int*)d_in[1];
    const float* edge_attr= (const float*)d_in[2];
    const float* W        = (const float*)d_in[3];
    const float* W_edge   = (const float*)d_in[4];
    const float* att_src  = (const float*)d_in[5];
    const float* att_dst  = (const float*)d_in[6];
    const float* att_edge = (const float*)d_in[7];
    const float* bias     = (const float*)d_in[8];
    const float* Wp       = (const float*)d_in[9];
    const float* bp       = (const float*)d_in[10];
    const float* gamma    = (const float*)d_in[11];
    const float* beta     = (const float*)d_in[12];
    float* out = (float*)d_out;

    int n = in_sizes[0] / EMB;
    int E = in_sizes[1] / 2;

    float* ws = (float*)d_ws;
    float* xw          = ws; ws += (size_t)n * HC;
    float* agg         = ws; ws += (size_t)n * HC;
    float* a_src       = ws; ws += (size_t)n * HEADS;
    float* a_dst       = ws; ws += (size_t)n * HEADS;
    float* node_ae_sum = ws; ws += (size_t)n * HEADS;
    float* amax        = ws; ws += (size_t)n * HEADS;
    float* denom       = ws; ws += (size_t)n * HEADS;
    float* alpha_loop  = ws; ws += (size_t)n * HEADS;
    float* cnt         = ws; ws += n;
    float* we_att      = ws; ws += EDGE_DIM * HEADS;
    float* alphabuf    = ws; ws += (size_t)E * HEADS;

    const int tb = 256;
    hipLaunchKernelGGL(k_init, dim3((n * HEADS + tb - 1) / tb), dim3(tb), 0, stream,
                       amax, node_ae_sum, denom, cnt, n);
    hipLaunchKernelGGL(k_we_att, dim3(1), dim3(64), 0, stream, W_edge, att_edge, we_att);
    hipLaunchKernelGGL(k_node_transform, dim3(n), dim3(HC), 0, stream,
                       x, W, att_src, att_dst, xw, a_src, a_dst);
    hipLaunchKernelGGL(k_edge1, dim3((E + tb - 1) / tb), dim3(tb), 0, stream,
                       ei, edge_attr, we_att, a_src, a_dst, alphabuf, amax, node_ae_sum, cnt, E);
    hipLaunchKernelGGL(k_node_loop, dim3((n * HEADS + tb - 1) / tb), dim3(tb), 0, stream,
                       a_src, a_dst, node_ae_sum, cnt, amax, alpha_loop, n);
    hipLaunchKernelGGL(k_edge2, dim3((E + tb - 1) / tb), dim3(tb), 0, stream,
                       ei, alphabuf, amax, denom, E);
    hipLaunchKernelGGL(k_node_agg_init, dim3(n), dim3(HC), 0, stream,
                       alpha_loop, amax, denom, xw, agg);
    hipLaunchKernelGGL(k_edge3, dim3(E), dim3(HC), 0, stream,
                       ei, alphabuf, denom, xw, agg, E);
    hipLaunchKernelGGL(k_out, dim3(n), dim3(HC), 0, stream,
                       x, agg, bias, Wp, bp, gamma, beta, out);
}

// Round 2
// 600.561 us; speedup vs baseline: 2.4001x; 2.4001x over previous
//
#include <hip/hip_runtime.h>
#include <math.h>

#define EMB 64
#define HEADS 4
#define HC 256
#define EDGE_DIM 16
#define NEG_SLOPE 0.2f
#define LN_EPS 1e-5f
#define CH 64   // gather chunk size (edges staged in LDS at a time)

// ---------------- init: zero cnt, fill, node_ae_sum ----------------
__global__ void k_init(int* cnt, int* fill, float* node_ae_sum, int n) {
    int i = blockIdx.x * blockDim.x + threadIdx.x;
    if (i < n) { cnt[i] = 0; fill[i] = 0; }
    if (i < n * HEADS) node_ae_sum[i] = 0.0f;
}

// we_att[d,h] = sum_c W_edge[d, h*64+c] * att_edge[h,c]   (16x4)
__global__ void k_we_att(const float* __restrict__ W_edge, const float* __restrict__ att_edge,
                         float* __restrict__ we_att) {
    int tid = threadIdx.x; // 64 threads
    int d = tid >> 2, h = tid & 3;
    float acc = 0.0f;
#pragma unroll
    for (int c = 0; c < EMB; ++c)
        acc += W_edge[d * HC + h * EMB + c] * att_edge[h * EMB + c];
    we_att[d * HEADS + h] = acc;
}

// xw = x @ W  (block per node, 256 threads); fused a_src/a_dst per-head reductions
__global__ void k_node_transform(const float* __restrict__ x, const float* __restrict__ W,
                                 const float* __restrict__ att_src, const float* __restrict__ att_dst,
                                 float* __restrict__ xw, float* __restrict__ a_src,
                                 float* __restrict__ a_dst) {
    int node = blockIdx.x;
    int tid = threadIdx.x;
    __shared__ float xs[EMB];
    if (tid < EMB) xs[tid] = x[node * EMB + tid];
    __syncthreads();
    float acc = 0.0f;
#pragma unroll
    for (int k = 0; k < EMB; ++k) acc += xs[k] * W[k * HC + tid];
    xw[(size_t)node * HC + tid] = acc;
    int h = tid >> 6, c = tid & 63;
    float vs = acc * att_src[tid];
    float vd = acc * att_dst[tid];
    for (int off = 32; off > 0; off >>= 1) {
        vs += __shfl_down(vs, off);
        vd += __shfl_down(vd, off);
    }
    if (c == 0) { a_src[node * HEADS + h] = vs; a_dst[node * HEADS + h] = vd; }
}

// ---------------- histogram of dst ----------------
__global__ void k_hist(const int* __restrict__ ei, int* __restrict__ cnt, int E) {
    int e = blockIdx.x * blockDim.x + threadIdx.x;
    if (e < E) atomicAdd(&cnt[ei[E + e]], 1);
}

// ---------------- 3-dispatch exclusive scan over cnt[n] ----------------
__global__ void k_scan1(const int* __restrict__ cnt, int* __restrict__ tmp,
                        int* __restrict__ bsum, int n) {
    __shared__ int s[256];
    int i = blockIdx.x * 256 + threadIdx.x;
    int v = (i < n) ? cnt[i] : 0;
    s[threadIdx.x] = v;
    __syncthreads();
    // Hillis-Steele inclusive scan
    for (int off = 1; off < 256; off <<= 1) {
        int t = (threadIdx.x >= off) ? s[threadIdx.x - off] : 0;
        __syncthreads();
        s[threadIdx.x] += t;
        __syncthreads();
    }
    if (i < n) tmp[i] = s[threadIdx.x];
    if (threadIdx.x == 255) bsum[blockIdx.x] = s[255];
}

__global__ void k_scan2(int* __restrict__ bsum, int nb) {
    __shared__ int s[256];
    int v = (threadIdx.x < nb) ? bsum[threadIdx.x] : 0;
    s[threadIdx.x] = v;
    __syncthreads();
    for (int off = 1; off < 256; off <<= 1) {
        int t = (threadIdx.x >= off) ? s[threadIdx.x - off] : 0;
        __syncthreads();
        s[threadIdx.x] += t;
        __syncthreads();
    }
    if (threadIdx.x < nb) bsum[threadIdx.x] = s[threadIdx.x] - v; // exclusive
}

__global__ void k_scan3(const int* __restrict__ tmp, const int* __restrict__ cnt,
                        const int* __restrict__ bsum, int* __restrict__ row_start, int n) {
    int i = blockIdx.x * 256 + threadIdx.x;
    if (i < n) row_start[i] = tmp[i] - cnt[i] + bsum[blockIdx.x];
}

// ---------------- edge pass: alpha + CSR scatter ----------------
__global__ void k_scatter(const int* __restrict__ ei, const float* __restrict__ edge_attr,
                          const float* __restrict__ we_att, const float* __restrict__ a_src,
                          const float* __restrict__ a_dst, const int* __restrict__ row_start,
                          int* __restrict__ fill, float* __restrict__ node_ae_sum,
                          int* __restrict__ srcp, float* __restrict__ alphap, int E) {
    __shared__ float wa[EDGE_DIM * HEADS];
    if (threadIdx.x < EDGE_DIM * HEADS) wa[threadIdx.x] = we_att[threadIdx.x];
    __syncthreads();
    int e = blockIdx.x * blockDim.x + threadIdx.x;
    if (e >= E) return;
    int s = ei[e], d = ei[E + e];
    const float4* ea4 = (const float4*)(edge_attr + (size_t)e * EDGE_DIM);
    float ae[HEADS] = {0.f, 0.f, 0.f, 0.f};
#pragma unroll
    for (int q = 0; q < 4; ++q) {
        float4 v4 = ea4[q];
        const float* vp = (const float*)&v4;
#pragma unroll
        for (int r = 0; r < 4; ++r) {
            float v = vp[r];
            int dd = q * 4 + r;
#pragma unroll
            for (int h = 0; h < HEADS; ++h) ae[h] += v * wa[dd * HEADS + h];
        }
    }
    float4 al4;
    float* alp = (float*)&al4;
#pragma unroll
    for (int h = 0; h < HEADS; ++h) {
        atomicAdd(&node_ae_sum[d * HEADS + h], ae[h]);
        float al = a_src[s * HEADS + h] + a_dst[d * HEADS + h] + ae[h];
        alp[h] = al >= 0.0f ? al : NEG_SLOPE * al;
    }
    int pos = row_start[d] + atomicAdd(&fill[d], 1);
    srcp[pos] = s;
    *(float4*)(alphap + (size_t)pos * HEADS) = al4;
}

// ---------------- fused gather + softmax + aggregate + epilogue ----------------
__global__ void k_gather_out(const int* __restrict__ row_start, const int* __restrict__ cnt,
                             const int* __restrict__ srcp, const float* __restrict__ alphap,
                             const float* __restrict__ node_ae_sum, const float* __restrict__ a_src,
                             const float* __restrict__ a_dst, const float* __restrict__ xw,
                             const float* __restrict__ x, const float* __restrict__ bias,
                             const float* __restrict__ Wp, const float* __restrict__ bp,
                             const float* __restrict__ gamma, const float* __restrict__ beta,
                             float* __restrict__ out) {
    int node = blockIdx.x;
    int tid = threadIdx.x;
    __shared__ float m_s[HEADS], dn_s[HEADS], at_loop_s[HEADS];
    __shared__ int srcs[CH];
    __shared__ float attn_c[CH][HEADS];
    __shared__ float g[HC];
    __shared__ float ps[HC];

    int rs = row_start[node];
    int dg = cnt[node];

    // ---- pass A: per-head max & denom (first wave only) ----
    if (tid < 64) {
        float alo[HEADS], m[HEADS], sum[HEADS];
        float cf = fmaxf((float)dg, 1.0f);
#pragma unroll
        for (int h = 0; h < HEADS; ++h) {
            float ael = node_ae_sum[node * HEADS + h] / cf;
            float al = a_src[node * HEADS + h] + a_dst[node * HEADS + h] + ael;
            alo[h] = al >= 0.0f ? al : NEG_SLOPE * al;
            m[h] = alo[h];
        }
        for (int j = tid; j < dg; j += 64) {
            float4 a4 = *(const float4*)(alphap + (size_t)(rs + j) * HEADS);
            const float* ap = (const float*)&a4;
#pragma unroll
            for (int h = 0; h < HEADS; ++h) m[h] = fmaxf(m[h], ap[h]);
        }
#pragma unroll
        for (int h = 0; h < HEADS; ++h)
            for (int off = 32; off > 0; off >>= 1)
                m[h] = fmaxf(m[h], __shfl_xor(m[h], off));
#pragma unroll
        for (int h = 0; h < HEADS; ++h)
            sum[h] = (tid == 0) ? __expf(alo[h] - m[h]) : 0.0f;
        for (int j = tid; j < dg; j += 64) {
            float4 a4 = *(const float4*)(alphap + (size_t)(rs + j) * HEADS);
            const float* ap = (const float*)&a4;
#pragma unroll
            for (int h = 0; h < HEADS; ++h) sum[h] += __expf(ap[h] - m[h]);
        }
#pragma unroll
        for (int h = 0; h < HEADS; ++h)
            for (int off = 32; off > 0; off >>= 1)
                sum[h] += __shfl_xor(sum[h], off);
        if (tid == 0) {
#pragma unroll
            for (int h = 0; h < HEADS; ++h) {
                m_s[h] = m[h];
                dn_s[h] = sum[h];
                at_loop_s[h] = __expf(alo[h] - m[h]) / sum[h];
            }
        }
    }
    __syncthreads();

    int h = tid >> 6;
    float acc = at_loop_s[h] * xw[(size_t)node * HC + tid];

    // ---- pass B: chunked aggregation ----
    for (int base = 0; base < dg; base += CH) {
        int c = min(CH, dg - base);
        if (tid < c) {
            srcs[tid] = srcp[rs + base + tid];
            float4 a4 = *(const float4*)(alphap + (size_t)(rs + base + tid) * HEADS);
            const float* ap = (const float*)&a4;
#pragma unroll
            for (int hh = 0; hh < HEADS; ++hh)
                attn_c[tid][hh] = __expf(ap[hh] - m_s[hh]) / dn_s[hh];
        }
        __syncthreads();
        for (int j = 0; j < c; ++j)
            acc += attn_c[j][h] * xw[(size_t)srcs[j] * HC + tid];
        __syncthreads();
    }

    // ---- epilogue: +bias -> @Wp -> elu -> residual -> LN ----
    g[tid] = acc + bias[tid];
    __syncthreads();
    int k = tid & 63, part = tid >> 6;
    float pacc = 0.0f;
#pragma unroll
    for (int j = 0; j < 64; ++j) {
        int jj = part * 64 + j;
        pacc += g[jj] * Wp[jj * EMB + k];
    }
    ps[tid] = pacc;
    __syncthreads();
    if (tid < EMB) {
        float p = ps[k] + ps[64 + k] + ps[128 + k] + ps[192 + k] + bp[k];
        float el = p > 0.0f ? p : expm1f(p);
        float hv = x[(size_t)node * EMB + k] + el;
        float s1 = hv, s2 = hv * hv;
        for (int off = 32; off > 0; off >>= 1) {
            s1 += __shfl_xor(s1, off);
            s2 += __shfl_xor(s2, off);
        }
        float mu = s1 * (1.0f / EMB);
        float var = s2 * (1.0f / EMB) - mu * mu;
        out[(size_t)node * EMB + k] = (hv - mu) * rsqrtf(var + LN_EPS) * gamma[k] + beta[k];
    }
}

extern "C" void kernel_launch(void* const* d_in, const int* in_sizes, int n_in,
                              void* d_out, int out_size, void* d_ws, size_t ws_size,
                              hipStream_t stream) {
    const float* x        = (const float*)d_in[0];
    const int*   ei       = (const int*)d_in[1];
    const float* edge_attr= (const float*)d_in[2];
    const float* W        = (const float*)d_in[3];
    const float* W_edge   = (const float*)d_in[4];
    const float* att_src  = (const float*)d_in[5];
    const float* att_dst  = (const float*)d_in[6];
    const float* att_edge = (const float*)d_in[7];
    const float* bias     = (const float*)d_in[8];
    const float* Wp       = (const float*)d_in[9];
    const float* bp       = (const float*)d_in[10];
    const float* gamma    = (const float*)d_in[11];
    const float* beta     = (const float*)d_in[12];
    float* out = (float*)d_out;

    int n = in_sizes[0] / EMB;
    int E = in_sizes[1] / 2;
    int nb = (n + 255) / 256;

    float* ws = (float*)d_ws;
    float* xw          = ws; ws += (size_t)n * HC;
    float* a_src       = ws; ws += (size_t)n * HEADS;
    float* a_dst       = ws; ws += (size_t)n * HEADS;
    float* node_ae_sum = ws; ws += (size_t)n * HEADS;
    float* we_att      = ws; ws += EDGE_DIM * HEADS;
    float* alphap      = ws; ws += (size_t)E * HEADS;
    int* iw = (int*)ws;
    int* cnt       = iw; iw += n;
    int* fill      = iw; iw += n;
    int* row_start = iw; iw += n;
    int* tmp       = iw; iw += n;
    int* bsum      = iw; iw += 256;
    int* srcp      = iw; iw += E;

    const int tb = 256;
    hipLaunchKernelGGL(k_init, dim3((n * HEADS + tb - 1) / tb), dim3(tb), 0, stream,
                       cnt, fill, node_ae_sum, n);
    hipLaunchKernelGGL(k_we_att, dim3(1), dim3(64), 0, stream, W_edge, att_edge, we_att);
    hipLaunchKernelGGL(k_node_transform, dim3(n), dim3(HC), 0, stream,
                       x, W, att_src, att_dst, xw, a_src, a_dst);
    hipLaunchKernelGGL(k_hist, dim3((E + tb - 1) / tb), dim3(tb), 0, stream, ei, cnt, E);
    hipLaunchKernelGGL(k_scan1, dim3(nb), dim3(tb), 0, stream, cnt, tmp, bsum, n);
    hipLaunchKernelGGL(k_scan2, dim3(1), dim3(tb), 0, stream, bsum, nb);
    hipLaunchKernelGGL(k_scan3, dim3(nb), dim3(tb), 0, stream, tmp, cnt, bsum, row_start, n);
    hipLaunchKernelGGL(k_scatter, dim3((E + tb - 1) / tb), dim3(tb), 0, stream,
                       ei, edge_attr, we_att, a_src, a_dst, row_start, fill,
                       node_ae_sum, srcp, alphap, E);
    hipLaunchKernelGGL(k_gather_out, dim3(n), dim3(HC), 0, stream,
                       row_start, cnt, srcp, alphap, node_ae_sum, a_src, a_dst,
                       xw, x, bias, Wp, bp, gamma, beta, out);
}

// Round 3
// 552.132 us; speedup vs baseline: 2.6106x; 1.0877x over previous
//
#include <hip/hip_runtime.h>
#include <hip/hip_bf16.h>
#include <math.h>

#define EMB 64
#define HEADS 4
#define HC 256
#define EDGE_DIM 16
#define NEG_SLOPE 0.2f
#define LN_EPS 1e-5f
#define CH 64   // gather chunk size (edges staged in LDS at a time)

// ---------------- init: zero cnt, fill, node_ae_sum ----------------
__global__ void k_init(int* cnt, int* fill, float* node_ae_sum, int n) {
    int i = blockIdx.x * blockDim.x + threadIdx.x;
    if (i < n) { cnt[i] = 0; fill[i] = 0; }
    if (i < n * HEADS) node_ae_sum[i] = 0.0f;
}

// we_att[d,h] = sum_c W_edge[d, h*64+c] * att_edge[h,c]   (16x4)
__global__ void k_we_att(const float* __restrict__ W_edge, const float* __restrict__ att_edge,
                         float* __restrict__ we_att) {
    int tid = threadIdx.x; // 64 threads
    int d = tid >> 2, h = tid & 3;
    float acc = 0.0f;
#pragma unroll
    for (int c = 0; c < EMB; ++c)
        acc += W_edge[d * HC + h * EMB + c] * att_edge[h * EMB + c];
    we_att[d * HEADS + h] = acc;
}

// xw = x @ W (block per node); store bf16; fused a_src/a_dst per-head reductions (fp32)
__global__ void k_node_transform(const float* __restrict__ x, const float* __restrict__ W,
                                 const float* __restrict__ att_src, const float* __restrict__ att_dst,
                                 __hip_bfloat16* __restrict__ xwb, float* __restrict__ a_src,
                                 float* __restrict__ a_dst) {
    int node = blockIdx.x;
    int tid = threadIdx.x;
    __shared__ float xs[EMB];
    if (tid < EMB) xs[tid] = x[node * EMB + tid];
    __syncthreads();
    float acc = 0.0f;
#pragma unroll
    for (int k = 0; k < EMB; ++k) acc += xs[k] * W[k * HC + tid];
    xwb[(size_t)node * HC + tid] = __float2bfloat16(acc);
    int h = tid >> 6, c = tid & 63;
    float vs = acc * att_src[tid];
    float vd = acc * att_dst[tid];
    for (int off = 32; off > 0; off >>= 1) {
        vs += __shfl_down(vs, off);
        vd += __shfl_down(vd, off);
    }
    if (c == 0) { a_src[node * HEADS + h] = vs; a_dst[node * HEADS + h] = vd; }
}

// ---------------- histogram of dst ----------------
__global__ void k_hist(const int* __restrict__ ei, int* __restrict__ cnt, int E) {
    int e = blockIdx.x * blockDim.x + threadIdx.x;
    if (e < E) atomicAdd(&cnt[ei[E + e]], 1);
}

// ---------------- 3-dispatch exclusive scan over cnt[n] ----------------
__global__ void k_scan1(const int* __restrict__ cnt, int* __restrict__ tmp,
                        int* __restrict__ bsum, int n) {
    __shared__ int s[256];
    int i = blockIdx.x * 256 + threadIdx.x;
    int v = (i < n) ? cnt[i] : 0;
    s[threadIdx.x] = v;
    __syncthreads();
    for (int off = 1; off < 256; off <<= 1) {
        int t = (threadIdx.x >= off) ? s[threadIdx.x - off] : 0;
        __syncthreads();
        s[threadIdx.x] += t;
        __syncthreads();
    }
    if (i < n) tmp[i] = s[threadIdx.x];
    if (threadIdx.x == 255) bsum[blockIdx.x] = s[255];
}

__global__ void k_scan2(int* __restrict__ bsum, int nb) {
    __shared__ int s[256];
    int v = (threadIdx.x < nb) ? bsum[threadIdx.x] : 0;
    s[threadIdx.x] = v;
    __syncthreads();
    for (int off = 1; off < 256; off <<= 1) {
        int t = (threadIdx.x >= off) ? s[threadIdx.x - off] : 0;
        __syncthreads();
        s[threadIdx.x] += t;
        __syncthreads();
    }
    if (threadIdx.x < nb) bsum[threadIdx.x] = s[threadIdx.x] - v; // exclusive
}

__global__ void k_scan3(const int* __restrict__ tmp, const int* __restrict__ cnt,
                        const int* __restrict__ bsum, int* __restrict__ row_start, int n) {
    int i = blockIdx.x * 256 + threadIdx.x;
    if (i < n) row_start[i] = tmp[i] - cnt[i] + bsum[blockIdx.x];
}

// ---------------- edge pass: exp(leaky(alpha)) + CSR scatter ----------------
__global__ void k_scatter(const int* __restrict__ ei, const float* __restrict__ edge_attr,
                          const float* __restrict__ we_att, const float* __restrict__ a_src,
                          const float* __restrict__ a_dst, const int* __restrict__ row_start,
                          int* __restrict__ fill, float* __restrict__ node_ae_sum,
                          int* __restrict__ srcp, float* __restrict__ alphap, int E) {
    __shared__ float wa[EDGE_DIM * HEADS];
    if (threadIdx.x < EDGE_DIM * HEADS) wa[threadIdx.x] = we_att[threadIdx.x];
    __syncthreads();
    int e = blockIdx.x * blockDim.x + threadIdx.x;
    if (e >= E) return;
    int s = ei[e], d = ei[E + e];
    const float4* ea4 = (const float4*)(edge_attr + (size_t)e * EDGE_DIM);
    float ae[HEADS] = {0.f, 0.f, 0.f, 0.f};
#pragma unroll
    for (int q = 0; q < 4; ++q) {
        float4 v4 = ea4[q];
        const float* vp = (const float*)&v4;
#pragma unroll
        for (int r = 0; r < 4; ++r) {
            float v = vp[r];
            int dd = q * 4 + r;
#pragma unroll
            for (int h = 0; h < HEADS; ++h) ae[h] += v * wa[dd * HEADS + h];
        }
    }
    float4 al4;
    float* alp = (float*)&al4;
#pragma unroll
    for (int h = 0; h < HEADS; ++h) {
        atomicAdd(&node_ae_sum[d * HEADS + h], ae[h]);
        float al = a_src[s * HEADS + h] + a_dst[d * HEADS + h] + ae[h];
        al = al >= 0.0f ? al : NEG_SLOPE * al;
        alp[h] = __expf(al);          // store exp(leaky(alpha)) — no max needed, |al|<~7
    }
    int pos = row_start[d] + atomicAdd(&fill[d], 1);
    srcp[pos] = s;
    *(float4*)(alphap + (size_t)pos * HEADS) = al4;
}

// ------- fused gather + online-denominator softmax + aggregate + epilogue -------
__global__ void k_gather_out(const int* __restrict__ row_start, const int* __restrict__ cnt,
                             const int* __restrict__ srcp, const float* __restrict__ alphap,
                             const float* __restrict__ node_ae_sum, const float* __restrict__ a_src,
                             const float* __restrict__ a_dst, const __hip_bfloat16* __restrict__ xwb,
                             const float* __restrict__ x, const float* __restrict__ bias,
                             const float* __restrict__ Wp, const float* __restrict__ bp,
                             const float* __restrict__ gamma, const float* __restrict__ beta,
                             float* __restrict__ out) {
    int node = blockIdx.x;
    int tid = threadIdx.x;
    __shared__ int srcs[CH];
    __shared__ float attn_c[CH][HEADS];
    __shared__ float g[HC];
    __shared__ float ps[HC];

    int rs = row_start[node];
    int dg = cnt[node];
    int h = tid >> 6;

    // self-loop term (per head, computed redundantly across the 64 lanes of each head)
    float ael = node_ae_sum[node * HEADS + h] / fmaxf((float)dg, 1.0f);
    float al = a_src[node * HEADS + h] + a_dst[node * HEADS + h] + ael;
    al = al >= 0.0f ? al : NEG_SLOPE * al;
    float el = __expf(al);
    float acc = el * __bfloat162float(xwb[(size_t)node * HC + tid]);
    float dn = el;

    // chunked aggregation with online denominator
    for (int base = 0; base < dg; base += CH) {
        int c = min(CH, dg - base);
        if (tid < c) {
            srcs[tid] = srcp[rs + base + tid];
            float4 a4 = *(const float4*)(alphap + (size_t)(rs + base + tid) * HEADS);
            *(float4*)&attn_c[tid][0] = a4;
        }
        __syncthreads();
        for (int j = 0; j < c; ++j) {
            float a = attn_c[j][h];
            acc += a * __bfloat162float(xwb[(size_t)srcs[j] * HC + tid]);
            dn += a;
        }
        __syncthreads();
    }
    acc /= dn;

    // ---- epilogue: +bias -> @Wp -> elu -> residual -> LN ----
    g[tid] = acc + bias[tid];
    __syncthreads();
    int k = tid & 63, part = tid >> 6;
    float pacc = 0.0f;
#pragma unroll
    for (int j = 0; j < 64; ++j) {
        int jj = part * 64 + j;
        pacc += g[jj] * Wp[jj * EMB + k];
    }
    ps[tid] = pacc;
    __syncthreads();
    if (tid < EMB) {
        float p = ps[k] + ps[64 + k] + ps[128 + k] + ps[192 + k] + bp[k];
        float elv = p > 0.0f ? p : expm1f(p);
        float hv = x[(size_t)node * EMB + k] + elv;
        float s1 = hv, s2 = hv * hv;
        for (int off = 32; off > 0; off >>= 1) {
            s1 += __shfl_xor(s1, off);
            s2 += __shfl_xor(s2, off);
        }
        float mu = s1 * (1.0f / EMB);
        float var = s2 * (1.0f / EMB) - mu * mu;
        out[(size_t)node * EMB + k] = (hv - mu) * rsqrtf(var + LN_EPS) * gamma[k] + beta[k];
    }
}

extern "C" void kernel_launch(void* const* d_in, const int* in_sizes, int n_in,
                              void* d_out, int out_size, void* d_ws, size_t ws_size,
                              hipStream_t stream) {
    const float* x        = (const float*)d_in[0];
    const int*   ei       = (const int*)d_in[1];
    const float* edge_attr= (const float*)d_in[2];
    const float* W        = (const float*)d_in[3];
    const float* W_edge   = (const float*)d_in[4];
    const float* att_src  = (const float*)d_in[5];
    const float* att_dst  = (const float*)d_in[6];
    const float* att_edge = (const float*)d_in[7];
    const float* bias     = (const float*)d_in[8];
    const float* Wp       = (const float*)d_in[9];
    const float* bp       = (const float*)d_in[10];
    const float* gamma    = (const float*)d_in[11];
    const float* beta     = (const float*)d_in[12];
    float* out = (float*)d_out;

    int n = in_sizes[0] / EMB;
    int E = in_sizes[1] / 2;
    int nb = (n + 255) / 256;

    float* ws = (float*)d_ws;
    float* alphap      = ws; ws += (size_t)E * HEADS;      // 16B-aligned (base)
    float* a_src       = ws; ws += (size_t)n * HEADS;
    float* a_dst       = ws; ws += (size_t)n * HEADS;
    float* node_ae_sum = ws; ws += (size_t)n * HEADS;
    float* we_att      = ws; ws += EDGE_DIM * HEADS;
    __hip_bfloat16* xwb = (__hip_bfloat16*)ws; ws += (size_t)n * HC / 2;
    int* iw = (int*)ws;
    int* cnt       = iw; iw += n;
    int* fill      = iw; iw += n;
    int* row_start = iw; iw += n;
    int* tmp       = iw; iw += n;
    int* bsum      = iw; iw += 256;
    int* srcp      = iw; iw += E;

    const int tb = 256;
    hipLaunchKernelGGL(k_init, dim3((n * HEADS + tb - 1) / tb), dim3(tb), 0, stream,
                       cnt, fill, node_ae_sum, n);
    hipLaunchKernelGGL(k_we_att, dim3(1), dim3(64), 0, stream, W_edge, att_edge, we_att);
    hipLaunchKernelGGL(k_node_transform, dim3(n), dim3(HC), 0, stream,
                       x, W, att_src, att_dst, xwb, a_src, a_dst);
    hipLaunchKernelGGL(k_hist, dim3((E + tb - 1) / tb), dim3(tb), 0, stream, ei, cnt, E);
    hipLaunchKernelGGL(k_scan1, dim3(nb), dim3(tb), 0, stream, cnt, tmp, bsum, n);
    hipLaunchKernelGGL(k_scan2, dim3(1), dim3(tb), 0, stream, bsum, nb);
    hipLaunchKernelGGL(k_scan3, dim3(nb), dim3(tb), 0, stream, tmp, cnt, bsum, row_start, n);
    hipLaunchKernelGGL(k_scatter, dim3((E + tb - 1) / tb), dim3(tb), 0, stream,
                       ei, edge_attr, we_att, a_src, a_dst, row_start, fill,
                       node_ae_sum, srcp, alphap, E);
    hipLaunchKernelGGL(k_gather_out, dim3(n), dim3(HC), 0, stream,
                       row_start, cnt, srcp, alphap, node_ae_sum, a_src, a_dst,
                       xwb, x, bias, Wp, bp, gamma, beta, out);
}

// Round 4
// 409.349 us; speedup vs baseline: 3.5212x; 1.3488x over previous
//
#include <hip/hip_runtime.h>
#include <hip/hip_bf16.h>
#include <math.h>

#define EMB 64
#define HEADS 4
#define HC 256
#define EDGE_DIM 16
#define NEG_SLOPE 0.2f
#define LN_EPS 1e-5f
#define CH 64   // gather chunk size (edges staged in LDS at a time)

__device__ __forceinline__ float bflo(unsigned int u) { return __uint_as_float(u << 16); }
__device__ __forceinline__ float bfhi(unsigned int u) { return __uint_as_float(u & 0xffff0000u); }
__device__ __forceinline__ unsigned int pack_bf2(float a, float b) {
    __hip_bfloat16 ha = __float2bfloat16(a), hb = __float2bfloat16(b);
    unsigned short ua = *(unsigned short*)&ha, ub = *(unsigned short*)&hb;
    return (unsigned int)ua | ((unsigned int)ub << 16);
}

// ---------------- init: zero cnt ----------------
__global__ void k_init(int* cnt, int n) {
    int i = blockIdx.x * blockDim.x + threadIdx.x;
    if (i < n) cnt[i] = 0;
}

// we_att[d,h] = sum_c W_edge[d, h*64+c] * att_edge[h,c]   (16x4)
__global__ void k_we_att(const float* __restrict__ W_edge, const float* __restrict__ att_edge,
                         float* __restrict__ we_att) {
    int tid = threadIdx.x; // 64 threads
    int d = tid >> 2, h = tid & 3;
    float acc = 0.0f;
#pragma unroll
    for (int c = 0; c < EMB; ++c)
        acc += W_edge[d * HC + h * EMB + c] * att_edge[h * EMB + c];
    we_att[d * HEADS + h] = acc;
}

// xw = x @ W (block per node); store bf16; fused a_src/a_dst per-head reductions (fp32)
__global__ void k_node_transform(const float* __restrict__ x, const float* __restrict__ W,
                                 const float* __restrict__ att_src, const float* __restrict__ att_dst,
                                 __hip_bfloat16* __restrict__ xwb, float* __restrict__ a_src,
                                 float* __restrict__ a_dst) {
    int node = blockIdx.x;
    int tid = threadIdx.x;
    __shared__ float xs[EMB];
    if (tid < EMB) xs[tid] = x[node * EMB + tid];
    __syncthreads();
    float acc = 0.0f;
#pragma unroll
    for (int k = 0; k < EMB; ++k) acc += xs[k] * W[k * HC + tid];
    xwb[(size_t)node * HC + tid] = __float2bfloat16(acc);
    int h = tid >> 6, c = tid & 63;
    float vs = acc * att_src[tid];
    float vd = acc * att_dst[tid];
    for (int off = 32; off > 0; off >>= 1) {
        vs += __shfl_down(vs, off);
        vd += __shfl_down(vd, off);
    }
    if (c == 0) { a_src[node * HEADS + h] = vs; a_dst[node * HEADS + h] = vd; }
}

// ---------------- histogram of dst + per-edge rank (the only atomic pass) ----------------
__global__ void k_hist(const int* __restrict__ ei, int* __restrict__ cnt,
                       int* __restrict__ rank, int E) {
    int e = blockIdx.x * blockDim.x + threadIdx.x;
    if (e < E) rank[e] = atomicAdd(&cnt[ei[E + e]], 1);
}

// ---------------- 3-dispatch exclusive scan over cnt[n] ----------------
__global__ void k_scan1(const int* __restrict__ cnt, int* __restrict__ tmp,
                        int* __restrict__ bsum, int n) {
    __shared__ int s[256];
    int i = blockIdx.x * 256 + threadIdx.x;
    int v = (i < n) ? cnt[i] : 0;
    s[threadIdx.x] = v;
    __syncthreads();
    for (int off = 1; off < 256; off <<= 1) {
        int t = (threadIdx.x >= off) ? s[threadIdx.x - off] : 0;
        __syncthreads();
        s[threadIdx.x] += t;
        __syncthreads();
    }
    if (i < n) tmp[i] = s[threadIdx.x];
    if (threadIdx.x == 255) bsum[blockIdx.x] = s[255];
}

__global__ void k_scan2(int* __restrict__ bsum, int nb) {
    __shared__ int s[256];
    int v = (threadIdx.x < nb) ? bsum[threadIdx.x] : 0;
    s[threadIdx.x] = v;
    __syncthreads();
    for (int off = 1; off < 256; off <<= 1) {
        int t = (threadIdx.x >= off) ? s[threadIdx.x - off] : 0;
        __syncthreads();
        s[threadIdx.x] += t;
        __syncthreads();
    }
    if (threadIdx.x < nb) bsum[threadIdx.x] = s[threadIdx.x] - v; // exclusive
}

__global__ void k_scan3(const int* __restrict__ tmp, const int* __restrict__ cnt,
                        const int* __restrict__ bsum, int* __restrict__ row_start, int n) {
    int i = blockIdx.x * 256 + threadIdx.x;
    if (i < n) row_start[i] = tmp[i] - cnt[i] + bsum[blockIdx.x];
}

// ---- edge pass: exp(leaky(alpha)), ae; pack 32B CSR record; NO atomics ----
// record (8 uints): [src][ea01][ea23][ae01] (uint4) + [ae23] (uint), rest pad
__global__ void k_scatter(const int* __restrict__ ei, const float* __restrict__ edge_attr,
                          const float* __restrict__ we_att, const float* __restrict__ a_src,
                          const float* __restrict__ a_dst, const int* __restrict__ row_start,
                          const int* __restrict__ rank, unsigned int* __restrict__ recp, int E) {
    __shared__ float wa[EDGE_DIM * HEADS];
    if (threadIdx.x < EDGE_DIM * HEADS) wa[threadIdx.x] = we_att[threadIdx.x];
    __syncthreads();
    int e = blockIdx.x * blockDim.x + threadIdx.x;
    if (e >= E) return;
    int s = ei[e], d = ei[E + e];
    const float4* ea4 = (const float4*)(edge_attr + (size_t)e * EDGE_DIM);
    float ae[HEADS] = {0.f, 0.f, 0.f, 0.f};
#pragma unroll
    for (int q = 0; q < 4; ++q) {
        float4 v4 = ea4[q];
        const float* vp = (const float*)&v4;
#pragma unroll
        for (int r = 0; r < 4; ++r) {
            float v = vp[r];
            int dd = q * 4 + r;
#pragma unroll
            for (int h = 0; h < HEADS; ++h) ae[h] += v * wa[dd * HEADS + h];
        }
    }
    float ea[HEADS];
#pragma unroll
    for (int h = 0; h < HEADS; ++h) {
        float al = a_src[s * HEADS + h] + a_dst[d * HEADS + h] + ae[h];
        al = al >= 0.0f ? al : NEG_SLOPE * al;
        ea[h] = __expf(al);          // no max-subtraction needed: |al| < ~8
    }
    int pos = row_start[d] + rank[e];
    size_t off = (size_t)pos * 8;
    uint4 w0;
    w0.x = (unsigned int)s;
    w0.y = pack_bf2(ea[0], ea[1]);
    w0.z = pack_bf2(ea[2], ea[3]);
    w0.w = pack_bf2(ae[0], ae[1]);
    *(uint4*)(recp + off) = w0;
    recp[off + 4] = pack_bf2(ae[2], ae[3]);
}

// ------- fused gather + softmax + aggregate + epilogue (wave-per-edge) -------
__global__ void __launch_bounds__(256)
k_gather_out(const int* __restrict__ row_start, const int* __restrict__ cnt,
             const unsigned int* __restrict__ recp, const float* __restrict__ a_src,
             const float* __restrict__ a_dst, const __hip_bfloat16* __restrict__ xwb,
             const float* __restrict__ x, const float* __restrict__ bias,
             const float* __restrict__ Wp, const float* __restrict__ bp,
             const float* __restrict__ gamma, const float* __restrict__ beta,
             float* __restrict__ out) {
    int node = blockIdx.x;
    int tid = threadIdx.x;
    int lane = tid & 63, wv = tid >> 6;
    int h4 = lane >> 4;                 // head for channels lane*4..lane*4+3

    __shared__ int srcs[CH];
    __shared__ float attn_s[CH][HEADS];
    __shared__ float4 red4[4][64];
    __shared__ float selfw_s[HEADS], dn_s[HEADS];
    __shared__ float g[HC];
    __shared__ float ps[HC];

    int rs = row_start[node];
    int dg = cnt[node];

    float acc0 = 0.f, acc1 = 0.f, acc2 = 0.f, acc3 = 0.f;
    float dnL0 = 0.f, dnL1 = 0.f, dnL2 = 0.f, dnL3 = 0.f;
    float aeL0 = 0.f, aeL1 = 0.f, aeL2 = 0.f, aeL3 = 0.f;

    const unsigned short* xwu = (const unsigned short*)xwb;

    for (int base = 0; base < dg; base += CH) {
        int c = min(CH, dg - base);
        if (tid < c) {                   // wave 0 stages
            size_t off = (size_t)(rs + base + tid) * 8;
            uint4 w0 = *(const uint4*)(recp + off);
            unsigned int w1 = recp[off + 4];
            srcs[tid] = (int)w0.x;
            float e0 = bflo(w0.y), e1 = bfhi(w0.y), e2 = bflo(w0.z), e3 = bfhi(w0.z);
            attn_s[tid][0] = e0; attn_s[tid][1] = e1;
            attn_s[tid][2] = e2; attn_s[tid][3] = e3;
            dnL0 += e0; dnL1 += e1; dnL2 += e2; dnL3 += e3;
            aeL0 += bflo(w0.w); aeL1 += bfhi(w0.w);
            aeL2 += bflo(w1);   aeL3 += bfhi(w1);
        }
        __syncthreads();
        for (int j = wv; j < c; j += 4) {
            int s = srcs[j];
            float a = attn_s[j][h4];
            ushort4 v = *(const ushort4*)(xwu + (size_t)s * HC + (lane << 2));
            acc0 += a * __uint_as_float((unsigned int)v.x << 16);
            acc1 += a * __uint_as_float((unsigned int)v.y << 16);
            acc2 += a * __uint_as_float((unsigned int)v.z << 16);
            acc3 += a * __uint_as_float((unsigned int)v.w << 16);
        }
        __syncthreads();
    }

    red4[wv][lane] = make_float4(acc0, acc1, acc2, acc3);

    if (tid < 64) {                      // wave 0: finish denominators + self loop
        for (int off = 32; off > 0; off >>= 1) {
            dnL0 += __shfl_xor(dnL0, off); dnL1 += __shfl_xor(dnL1, off);
            dnL2 += __shfl_xor(dnL2, off); dnL3 += __shfl_xor(dnL3, off);
            aeL0 += __shfl_xor(aeL0, off); aeL1 += __shfl_xor(aeL1, off);
            aeL2 += __shfl_xor(aeL2, off); aeL3 += __shfl_xor(aeL3, off);
        }
        if (lane == 0) {
            float dns[4] = {dnL0, dnL1, dnL2, dnL3};
            float aes[4] = {aeL0, aeL1, aeL2, aeL3};
            float cf = fmaxf((float)dg, 1.0f);
#pragma unroll
            for (int h = 0; h < HEADS; ++h) {
                float al = a_src[node * HEADS + h] + a_dst[node * HEADS + h] + aes[h] / cf;
                al = al >= 0.0f ? al : NEG_SLOPE * al;
                float el = __expf(al);
                selfw_s[h] = el;
                dn_s[h] = dns[h] + el;
            }
        }
    }
    __syncthreads();

    // final combine for channel `tid`
    const float* redf = (const float*)red4;
    float tot = redf[0 * HC + tid] + redf[1 * HC + tid] + redf[2 * HC + tid] + redf[3 * HC + tid];
    float xwn = __uint_as_float((unsigned int)xwu[(size_t)node * HC + tid] << 16);
    int hh = tid >> 6;
    g[tid] = (tot + selfw_s[hh] * xwn) / dn_s[hh] + bias[tid];
    __syncthreads();

    // ---- epilogue: @Wp -> elu -> residual -> LN ----
    int k = tid & 63, part = tid >> 6;
    float pacc = 0.0f;
#pragma unroll
    for (int j = 0; j < 64; ++j) {
        int jj = part * 64 + j;
        pacc += g[jj] * Wp[jj * EMB + k];
    }
    ps[tid] = pacc;
    __syncthreads();
    if (tid < EMB) {
        float p = ps[k] + ps[64 + k] + ps[128 + k] + ps[192 + k] + bp[k];
        float elv = p > 0.0f ? p : expm1f(p);
        float hv = x[(size_t)node * EMB + k] + elv;
        float s1 = hv, s2 = hv * hv;
        for (int off = 32; off > 0; off >>= 1) {
            s1 += __shfl_xor(s1, off);
            s2 += __shfl_xor(s2, off);
        }
        float mu = s1 * (1.0f / EMB);
        float var = s2 * (1.0f / EMB) - mu * mu;
        out[(size_t)node * EMB + k] = (hv - mu) * rsqrtf(var + LN_EPS) * gamma[k] + beta[k];
    }
}

extern "C" void kernel_launch(void* const* d_in, const int* in_sizes, int n_in,
                              void* d_out, int out_size, void* d_ws, size_t ws_size,
                              hipStream_t stream) {
    const float* x        = (const float*)d_in[0];
    const int*   ei       = (const int*)d_in[1];
    const float* edge_attr= (const float*)d_in[2];
    const float* W        = (const float*)d_in[3];
    const float* W_edge   = (const float*)d_in[4];
    const float* att_src  = (const float*)d_in[5];
    const float* att_dst  = (const float*)d_in[6];
    const float* att_edge = (const float*)d_in[7];
    const float* bias     = (const float*)d_in[8];
    const float* Wp       = (const float*)d_in[9];
    const float* bp       = (const float*)d_in[10];
    const float* gamma    = (const float*)d_in[11];
    const float* beta     = (const float*)d_in[12];
    float* out = (float*)d_out;

    int n = in_sizes[0] / EMB;
    int E = in_sizes[1] / 2;
    int nb = (n + 255) / 256;

    float* ws = (float*)d_ws;
    float* a_src       = ws; ws += (size_t)n * HEADS;
    float* a_dst       = ws; ws += (size_t)n * HEADS;
    float* we_att      = ws; ws += EDGE_DIM * HEADS;
    __hip_bfloat16* xwb = (__hip_bfloat16*)ws; ws += (size_t)n * HC / 2;
    unsigned int* recp = (unsigned int*)ws; ws += (size_t)E * 8;    // 32B/edge
    int* iw = (int*)ws;
    int* cnt       = iw; iw += n;
    int* rank      = iw; iw += E;
    int* row_start = iw; iw += n;
    int* tmp       = iw; iw += n;
    int* bsum      = iw; iw += 256;

    const int tb = 256;
    hipLaunchKernelGGL(k_init, dim3((n + tb - 1) / tb), dim3(tb), 0, stream, cnt, n);
    hipLaunchKernelGGL(k_we_att, dim3(1), dim3(64), 0, stream, W_edge, att_edge, we_att);
    hipLaunchKernelGGL(k_node_transform, dim3(n), dim3(HC), 0, stream,
                       x, W, att_src, att_dst, xwb, a_src, a_dst);
    hipLaunchKernelGGL(k_hist, dim3((E + tb - 1) / tb), dim3(tb), 0, stream, ei, cnt, rank, E);
    hipLaunchKernelGGL(k_scan1, dim3(nb), dim3(tb), 0, stream, cnt, tmp, bsum, n);
    hipLaunchKernelGGL(k_scan2, dim3(1), dim3(tb), 0, stream, bsum, nb);
    hipLaunchKernelGGL(k_scan3, dim3(nb), dim3(tb), 0, stream, tmp, cnt, bsum, row_start, n);
    hipLaunchKernelGGL(k_scatter, dim3((E + tb - 1) / tb), dim3(tb), 0, stream,
                       ei, edge_attr, we_att, a_src, a_dst, row_start, rank, recp, E);
    hipLaunchKernelGGL(k_gather_out, dim3(n), dim3(HC), 0, stream,
                       row_start, cnt, recp, a_src, a_dst, xwb, x, bias, Wp, bp,
                       gamma, beta, out);
}

// Round 5
// 281.681 us; speedup vs baseline: 5.1172x; 1.4532x over previous
//
#include <hip/hip_runtime.h>
#include <hip/hip_bf16.h>
#include <math.h>

#define EMB 64
#define HEADS 4
#define HC 256
#define EDGE_DIM 16
#define NEG_SLOPE 0.2f
#define LN_EPS 1e-5f

__device__ __forceinline__ float bflo(unsigned int u) { return __uint_as_float(u << 16); }
__device__ __forceinline__ float bfhi(unsigned int u) { return __uint_as_float(u & 0xffff0000u); }
__device__ __forceinline__ float bfu(unsigned short u) { return __uint_as_float((unsigned int)u << 16); }
__device__ __forceinline__ unsigned int pack_bf2(float a, float b) {
    __hip_bfloat16 ha = __float2bfloat16(a), hb = __float2bfloat16(b);
    unsigned short ua = *(unsigned short*)&ha, ub = *(unsigned short*)&hb;
    return (unsigned int)ua | ((unsigned int)ub << 16);
}

// ---------------- init: zero cnt ----------------
__global__ void k_init(int* cnt, int n) {
    int i = blockIdx.x * blockDim.x + threadIdx.x;
    if (i < n) cnt[i] = 0;
}

// we_att[d,h] = sum_c W_edge[d, h*64+c] * att_edge[h,c]; also Wp -> bf16
__global__ void k_prep(const float* __restrict__ W_edge, const float* __restrict__ att_edge,
                       float* __restrict__ we_att, const float* __restrict__ Wp,
                       unsigned short* __restrict__ WpB) {
    int i = blockIdx.x * blockDim.x + threadIdx.x;
    if (i < EDGE_DIM * HEADS) {
        int d = i >> 2, h = i & 3;
        float acc = 0.0f;
#pragma unroll
        for (int c = 0; c < EMB; ++c)
            acc += W_edge[d * HC + h * EMB + c] * att_edge[h * EMB + c];
        we_att[d * HEADS + h] = acc;
    }
    if (i < HC * EMB) {
        __hip_bfloat16 hb = __float2bfloat16(Wp[i]);
        WpB[i] = *(unsigned short*)&hb;
    }
}

// xw = x @ W (block per node); store bf16; fused a_src/a_dst per-head reductions (fp32)
__global__ void k_node_transform(const float* __restrict__ x, const float* __restrict__ W,
                                 const float* __restrict__ att_src, const float* __restrict__ att_dst,
                                 __hip_bfloat16* __restrict__ xwb, float* __restrict__ a_src,
                                 float* __restrict__ a_dst) {
    int node = blockIdx.x;
    int tid = threadIdx.x;
    __shared__ float xs[EMB];
    if (tid < EMB) xs[tid] = x[node * EMB + tid];
    __syncthreads();
    float acc = 0.0f;
#pragma unroll
    for (int k = 0; k < EMB; ++k) acc += xs[k] * W[k * HC + tid];
    xwb[(size_t)node * HC + tid] = __float2bfloat16(acc);
    int h = tid >> 6, c = tid & 63;
    float vs = acc * att_src[tid];
    float vd = acc * att_dst[tid];
    for (int off = 32; off > 0; off >>= 1) {
        vs += __shfl_down(vs, off);
        vd += __shfl_down(vd, off);
    }
    if (c == 0) { a_src[node * HEADS + h] = vs; a_dst[node * HEADS + h] = vd; }
}

// ---------------- histogram of dst + per-edge rank (the only atomic pass) ----------------
__global__ void k_hist(const int* __restrict__ ei, int* __restrict__ cnt,
                       int* __restrict__ rank, int E) {
    int e = blockIdx.x * blockDim.x + threadIdx.x;
    if (e < E) rank[e] = atomicAdd(&cnt[ei[E + e]], 1);
}

// ---------------- 3-dispatch exclusive scan over cnt[n] ----------------
__global__ void k_scan1(const int* __restrict__ cnt, int* __restrict__ tmp,
                        int* __restrict__ bsum, int n) {
    __shared__ int s[256];
    int i = blockIdx.x * 256 + threadIdx.x;
    int v = (i < n) ? cnt[i] : 0;
    s[threadIdx.x] = v;
    __syncthreads();
    for (int off = 1; off < 256; off <<= 1) {
        int t = (threadIdx.x >= off) ? s[threadIdx.x - off] : 0;
        __syncthreads();
        s[threadIdx.x] += t;
        __syncthreads();
    }
    if (i < n) tmp[i] = s[threadIdx.x];
    if (threadIdx.x == 255) bsum[blockIdx.x] = s[255];
}

__global__ void k_scan2(int* __restrict__ bsum, int nb) {
    __shared__ int s[256];
    int v = (threadIdx.x < nb) ? bsum[threadIdx.x] : 0;
    s[threadIdx.x] = v;
    __syncthreads();
    for (int off = 1; off < 256; off <<= 1) {
        int t = (threadIdx.x >= off) ? s[threadIdx.x - off] : 0;
        __syncthreads();
        s[threadIdx.x] += t;
        __syncthreads();
    }
    if (threadIdx.x < nb) bsum[threadIdx.x] = s[threadIdx.x] - v; // exclusive
}

__global__ void k_scan3(const int* __restrict__ tmp, const int* __restrict__ cnt,
                        const int* __restrict__ bsum, int* __restrict__ row_start, int n) {
    int i = blockIdx.x * 256 + threadIdx.x;
    if (i < n) row_start[i] = tmp[i] - cnt[i] + bsum[blockIdx.x];
}

// ---- edge pass: exp(leaky(alpha)), ae; pack 32B CSR record; NO atomics ----
// record (8 uints): [src][ea01][ea23][ae01] (uint4) + [ae23] (uint), rest pad
__global__ void k_scatter(const int* __restrict__ ei, const float* __restrict__ edge_attr,
                          const float* __restrict__ we_att, const float* __restrict__ a_src,
                          const float* __restrict__ a_dst, const int* __restrict__ row_start,
                          const int* __restrict__ rank, unsigned int* __restrict__ recp, int E) {
    __shared__ float wa[EDGE_DIM * HEADS];
    if (threadIdx.x < EDGE_DIM * HEADS) wa[threadIdx.x] = we_att[threadIdx.x];
    __syncthreads();
    int e = blockIdx.x * blockDim.x + threadIdx.x;
    if (e >= E) return;
    int s = ei[e], d = ei[E + e];
    const float4* ea4 = (const float4*)(edge_attr + (size_t)e * EDGE_DIM);
    float ae[HEADS] = {0.f, 0.f, 0.f, 0.f};
#pragma unroll
    for (int q = 0; q < 4; ++q) {
        float4 v4 = ea4[q];
        const float* vp = (const float*)&v4;
#pragma unroll
        for (int r = 0; r < 4; ++r) {
            float v = vp[r];
            int dd = q * 4 + r;
#pragma unroll
            for (int h = 0; h < HEADS; ++h) ae[h] += v * wa[dd * HEADS + h];
        }
    }
    float4 as4 = *(const float4*)(a_src + (size_t)s * HEADS);
    float4 ad4 = *(const float4*)(a_dst + (size_t)d * HEADS);
    const float* asp = (const float*)&as4;
    const float* adp = (const float*)&ad4;
    float ea[HEADS];
#pragma unroll
    for (int h = 0; h < HEADS; ++h) {
        float al = asp[h] + adp[h] + ae[h];
        al = al >= 0.0f ? al : NEG_SLOPE * al;
        ea[h] = __expf(al);          // no max-subtraction needed: |al| < ~8
    }
    int pos = row_start[d] + rank[e];
    size_t off = (size_t)pos * 8;
    uint4 w0;
    w0.x = (unsigned int)s;
    w0.y = pack_bf2(ea[0], ea[1]);
    w0.z = pack_bf2(ea[2], ea[3]);
    w0.w = pack_bf2(ae[0], ae[1]);
    *(uint4*)(recp + off) = w0;
    recp[off + 4] = pack_bf2(ae[2], ae[3]);
}

// ------- fused gather + softmax + aggregate + epilogue: 4 nodes/block, wave/node -------
#define PROC(A, B, R)                                                     \
    {                                                                     \
        unsigned ew = (h4 & 2) ? (A).z : (A).y;                           \
        unsigned aw = (h4 & 2) ? (B) : (A).w;                             \
        float a = (h4 & 1) ? bfhi(ew) : bflo(ew);                         \
        float ae = (h4 & 1) ? bfhi(aw) : bflo(aw);                        \
        dn += a; aeS += ae;                                               \
        acc0 += a * bfu((R).x); acc1 += a * bfu((R).y);                   \
        acc2 += a * bfu((R).z); acc3 += a * bfu((R).w);                   \
    }

__global__ void __launch_bounds__(256)
k_gather_out(const int* __restrict__ row_start, const int* __restrict__ cnt,
             const unsigned int* __restrict__ recp,
             const float* __restrict__ a_src, const float* __restrict__ a_dst,
             const __hip_bfloat16* __restrict__ xwb, const float* __restrict__ x,
             const float* __restrict__ bias, const unsigned short* __restrict__ WpB,
             const float* __restrict__ bp, const float* __restrict__ gamma,
             const float* __restrict__ beta, float* __restrict__ out, int n) {
    int tid = threadIdx.x, lane = tid & 63, wv = tid >> 6;
    int node = blockIdx.x * 4 + wv;
    bool valid = node < n;
    int nodeC = valid ? node : n - 1;
    int h4 = lane >> 4;

    __shared__ float gT[HC][4];      // [channel][node-in-block]
    __shared__ float psf[4][4][64];  // [nn][part][k]

    const unsigned short* xwu = (const unsigned short*)xwb;

    int rs = row_start[nodeC];
    int dg = valid ? cnt[nodeC] : 0;

    // hoisted self-node loads
    float as = a_src[nodeC * HEADS + h4];
    float ad = a_dst[nodeC * HEADS + h4];
    ushort4 sr = *(const ushort4*)(xwu + (size_t)nodeC * HC + (lane << 2));
    float4 bv = *(const float4*)(bias + (lane << 2));

    float acc0 = 0.f, acc1 = 0.f, acc2 = 0.f, acc3 = 0.f;
    float dn = 0.f, aeS = 0.f;

    const unsigned int* rp = recp + (size_t)rs * 8;
    int j = 0;
    for (; j + 4 <= dg; j += 4, rp += 32) {
        uint4 A0 = *(const uint4*)(rp);
        unsigned B0 = rp[4];
        uint4 A1 = *(const uint4*)(rp + 8);
        unsigned B1 = rp[12];
        uint4 A2 = *(const uint4*)(rp + 16);
        unsigned B2 = rp[20];
        uint4 A3 = *(const uint4*)(rp + 24);
        unsigned B3 = rp[28];
        ushort4 r0 = *(const ushort4*)(xwu + (size_t)A0.x * HC + (lane << 2));
        ushort4 r1 = *(const ushort4*)(xwu + (size_t)A1.x * HC + (lane << 2));
        ushort4 r2 = *(const ushort4*)(xwu + (size_t)A2.x * HC + (lane << 2));
        ushort4 r3 = *(const ushort4*)(xwu + (size_t)A3.x * HC + (lane << 2));
        PROC(A0, B0, r0)
        PROC(A1, B1, r1)
        PROC(A2, B2, r2)
        PROC(A3, B3, r3)
    }
    for (; j < dg; ++j, rp += 8) {
        uint4 A = *(const uint4*)(rp);
        unsigned B = rp[4];
        ushort4 r = *(const ushort4*)(xwu + (size_t)A.x * HC + (lane << 2));
        PROC(A, B, r)
    }

    // self-loop + normalize + bias; write to LDS
    float cf = fmaxf((float)dg, 1.0f);
    float al = as + ad + aeS / cf;
    al = al >= 0.f ? al : NEG_SLOPE * al;
    float el = __expf(al);
    float inv = 1.0f / (dn + el);
    int ch = lane << 2;
    gT[ch + 0][wv] = (acc0 + el * bfu(sr.x)) * inv + bv.x;
    gT[ch + 1][wv] = (acc1 + el * bfu(sr.y)) * inv + bv.y;
    gT[ch + 2][wv] = (acc2 + el * bfu(sr.z)) * inv + bv.z;
    gT[ch + 3][wv] = (acc3 + el * bfu(sr.w)) * inv + bv.w;
    __syncthreads();

    // projection: thread (part=wv, k=lane) does one quarter of the 256-dot for all 4 nodes
    int part = wv, k = lane;
    float p0 = 0.f, p1 = 0.f, p2 = 0.f, p3 = 0.f;
#pragma unroll 8
    for (int j2 = 0; j2 < 64; ++j2) {
        int jj = part * 64 + j2;
        float w = bfu(WpB[jj * EMB + k]);
        float4 gv = *(const float4*)&gT[jj][0];
        p0 += w * gv.x; p1 += w * gv.y; p2 += w * gv.z; p3 += w * gv.w;
    }
    psf[0][part][k] = p0;
    psf[1][part][k] = p1;
    psf[2][part][k] = p2;
    psf[3][part][k] = p3;
    __syncthreads();

    // final: wave wv handles its node; lane = channel k
    float p = psf[wv][0][lane] + psf[wv][1][lane] + psf[wv][2][lane] + psf[wv][3][lane] + bp[lane];
    float elv = p > 0.f ? p : expm1f(p);
    float xv = valid ? x[(size_t)node * EMB + lane] : 0.f;
    float hv = xv + elv;
    float s1 = hv, s2 = hv * hv;
    for (int off = 32; off > 0; off >>= 1) {
        s1 += __shfl_xor(s1, off);
        s2 += __shfl_xor(s2, off);
    }
    float mu = s1 * (1.0f / EMB);
    float var = s2 * (1.0f / EMB) - mu * mu;
    if (valid)
        out[(size_t)node * EMB + lane] = (hv - mu) * rsqrtf(var + LN_EPS) * gamma[lane] + beta[lane];
}

extern "C" void kernel_launch(void* const* d_in, const int* in_sizes, int n_in,
                              void* d_out, int out_size, void* d_ws, size_t ws_size,
                              hipStream_t stream) {
    const float* x        = (const float*)d_in[0];
    const int*   ei       = (const int*)d_in[1];
    const float* edge_attr= (const float*)d_in[2];
    const float* W        = (const float*)d_in[3];
    const float* W_edge   = (const float*)d_in[4];
    const float* att_src  = (const float*)d_in[5];
    const float* att_dst  = (const float*)d_in[6];
    const float* att_edge = (const float*)d_in[7];
    const float* bias     = (const float*)d_in[8];
    const float* Wp       = (const float*)d_in[9];
    const float* bp       = (const float*)d_in[10];
    const float* gamma    = (const float*)d_in[11];
    const float* beta     = (const float*)d_in[12];
    float* out = (float*)d_out;

    int n = in_sizes[0] / EMB;
    int E = in_sizes[1] / 2;
    int nb = (n + 255) / 256;

    float* ws = (float*)d_ws;
    float* a_src       = ws; ws += (size_t)n * HEADS;
    float* a_dst       = ws; ws += (size_t)n * HEADS;
    float* we_att      = ws; ws += EDGE_DIM * HEADS;
    __hip_bfloat16* xwb = (__hip_bfloat16*)ws; ws += (size_t)n * HC / 2;
    unsigned int* recp = (unsigned int*)ws; ws += (size_t)E * 8;    // 32B/edge
    unsigned short* WpB = (unsigned short*)ws; ws += HC * EMB / 2;
    int* iw = (int*)ws;
    int* cnt       = iw; iw += n;
    int* rank      = iw; iw += E;
    int* row_start = iw; iw += n;
    int* tmp       = iw; iw += n;
    int* bsum      = iw; iw += 256;

    const int tb = 256;
    hipLaunchKernelGGL(k_init, dim3((n + tb - 1) / tb), dim3(tb), 0, stream, cnt, n);
    hipLaunchKernelGGL(k_prep, dim3((HC * EMB + tb - 1) / tb), dim3(tb), 0, stream,
                       W_edge, att_edge, we_att, Wp, WpB);
    hipLaunchKernelGGL(k_node_transform, dim3(n), dim3(HC), 0, stream,
                       x, W, att_src, att_dst, xwb, a_src, a_dst);
    hipLaunchKernelGGL(k_hist, dim3((E + tb - 1) / tb), dim3(tb), 0, stream, ei, cnt, rank, E);
    hipLaunchKernelGGL(k_scan1, dim3(nb), dim3(tb), 0, stream, cnt, tmp, bsum, n);
    hipLaunchKernelGGL(k_scan2, dim3(1), dim3(tb), 0, stream, bsum, nb);
    hipLaunchKernelGGL(k_scan3, dim3(nb), dim3(tb), 0, stream, tmp, cnt, bsum, row_start, n);
    hipLaunchKernelGGL(k_scatter, dim3((E + tb - 1) / tb), dim3(tb), 0, stream,
                       ei, edge_attr, we_att, a_src, a_dst, row_start, rank, recp, E);
    hipLaunchKernelGGL(k_gather_out, dim3((n + 3) / 4), dim3(tb), 0, stream,
                       row_start, cnt, recp, a_src, a_dst, xwb, x, bias, WpB, bp,
                       gamma, beta, out, n);
}

// Round 6
// 203.215 us; speedup vs baseline: 7.0930x; 1.3861x over previous
//
#include <hip/hip_runtime.h>
#include <hip/hip_bf16.h>
#include <math.h>

#define EMB 64
#define HEADS 4
#define HC 256
#define EDGE_DIM 16
#define NEG_SLOPE 0.2f
#define LN_EPS 1e-5f
#define NCOLS 272   // 256 xw cols + 4 a_src + 4 a_dst + 8 pad

typedef __attribute__((ext_vector_type(8))) short short8;
typedef __attribute__((ext_vector_type(4))) float f32x4;

__device__ __forceinline__ float bflo(unsigned int u) { return __uint_as_float(u << 16); }
__device__ __forceinline__ float bfhi(unsigned int u) { return __uint_as_float(u & 0xffff0000u); }
__device__ __forceinline__ float bfu(unsigned short u) { return __uint_as_float((unsigned int)u << 16); }
__device__ __forceinline__ unsigned short bfb(float f) {
    __hip_bfloat16 h = __float2bfloat16(f);
    return *(unsigned short*)&h;
}
__device__ __forceinline__ unsigned int pack_bf2(float a, float b) {
    return (unsigned int)bfb(a) | ((unsigned int)bfb(b) << 16);
}

// ---------------- init: zero cnt ----------------
__global__ void k_init(int* cnt, int n) {
    int i = blockIdx.x * blockDim.x + threadIdx.x;
    if (i < n) cnt[i] = 0;
}

// we_att; Wp -> bf16; WxT[272][64] = [W^T | ws_src | ws_dst | 0] bf16
__global__ void k_prep(const float* __restrict__ W_edge, const float* __restrict__ att_edge,
                       float* __restrict__ we_att, const float* __restrict__ Wp,
                       unsigned short* __restrict__ WpB, const float* __restrict__ W,
                       const float* __restrict__ att_src, const float* __restrict__ att_dst,
                       unsigned short* __restrict__ WxT) {
    int i = blockIdx.x * blockDim.x + threadIdx.x;
    if (i < EDGE_DIM * HEADS) {
        int d = i >> 2, h = i & 3;
        float acc = 0.0f;
#pragma unroll
        for (int c = 0; c < EMB; ++c)
            acc += W_edge[d * HC + h * EMB + c] * att_edge[h * EMB + c];
        we_att[d * HEADS + h] = acc;
    }
    if (i < HC * EMB) WpB[i] = bfb(Wp[i]);
    if (i < NCOLS * EMB) {
        int c = i >> 6, k = i & 63;
        float v = 0.0f;
        if (c < HC) {
            v = W[k * HC + c];
        } else if (c < HC + 4) {
            int h = c - HC;
            float s = 0.0f;
#pragma unroll
            for (int j = 0; j < EMB; ++j) s += W[k * HC + h * EMB + j] * att_src[h * EMB + j];
            v = s;
        } else if (c < HC + 8) {
            int h = c - HC - 4;
            float s = 0.0f;
#pragma unroll
            for (int j = 0; j < EMB; ++j) s += W[k * HC + h * EMB + j] * att_dst[h * EMB + j];
            v = s;
        }
        WxT[i] = bfb(v);
    }
}

// ---- MFMA GEMM: [xw | a_src | a_dst] = x @ Wx ; 16 nodes/block, 4 waves ----
__global__ void __launch_bounds__(256)
k_xw_mfma(const float* __restrict__ x, const unsigned short* __restrict__ WxT,
          __hip_bfloat16* __restrict__ xwb, float* __restrict__ a_src,
          float* __restrict__ a_dst, int n) {
    int tid = threadIdx.x, lane = tid & 63, wv = tid >> 6;
    int g = lane >> 4, r16 = lane & 15;
    int mbase = blockIdx.x * 16;
    int row = mbase + r16;
    if (row >= n) row = n - 1;

    // A fragments: lane holds row (lane&15), k = kk*32 + 8*(lane>>4) + e (8 consecutive)
    const float* xr = x + (size_t)row * EMB;
    short8 A[2];
#pragma unroll
    for (int kk = 0; kk < 2; ++kk) {
        float4 f0 = *(const float4*)(xr + kk * 32 + 8 * g);
        float4 f1 = *(const float4*)(xr + kk * 32 + 8 * g + 4);
        short8 a;
        a[0] = (short)bfb(f0.x); a[1] = (short)bfb(f0.y);
        a[2] = (short)bfb(f0.z); a[3] = (short)bfb(f0.w);
        a[4] = (short)bfb(f1.x); a[5] = (short)bfb(f1.y);
        a[6] = (short)bfb(f1.z); a[7] = (short)bfb(f1.w);
        A[kk] = a;
    }

    for (int t = wv; t <= 16; t += 4) {
        int col = t * 16 + r16;
        const unsigned short* bp = WxT + (size_t)col * EMB + 8 * g;
        short8 B0 = *(const short8*)(bp);
        short8 B1 = *(const short8*)(bp + 32);
        f32x4 acc = {0.f, 0.f, 0.f, 0.f};
        acc = __builtin_amdgcn_mfma_f32_16x16x32_bf16(A[0], B0, acc, 0, 0, 0);
        acc = __builtin_amdgcn_mfma_f32_16x16x32_bf16(A[1], B1, acc, 0, 0, 0);
        if (t < 16) {
#pragma unroll
            for (int r = 0; r < 4; ++r) {
                int node = mbase + 4 * g + r;
                if (node < n) xwb[(size_t)node * HC + col] = __float2bfloat16(acc[r]);
            }
        } else {
#pragma unroll
            for (int r = 0; r < 4; ++r) {
                int node = mbase + 4 * g + r;
                if (node < n) {
                    if (r16 < 4) a_src[node * HEADS + r16] = acc[r];
                    else if (r16 < 8) a_dst[node * HEADS + r16 - 4] = acc[r];
                }
            }
        }
    }
}

// ---------------- histogram of dst + per-edge rank (the only atomic pass) ----------------
__global__ void k_hist(const int* __restrict__ ei, int* __restrict__ cnt,
                       int* __restrict__ rank, int E) {
    int e = blockIdx.x * blockDim.x + threadIdx.x;
    if (e < E) rank[e] = atomicAdd(&cnt[ei[E + e]], 1);
}

// ---------------- 3-dispatch exclusive scan over cnt[n] ----------------
__global__ void k_scan1(const int* __restrict__ cnt, int* __restrict__ tmp,
                        int* __restrict__ bsum, int n) {
    __shared__ int s[256];
    int i = blockIdx.x * 256 + threadIdx.x;
    int v = (i < n) ? cnt[i] : 0;
    s[threadIdx.x] = v;
    __syncthreads();
    for (int off = 1; off < 256; off <<= 1) {
        int t = (threadIdx.x >= off) ? s[threadIdx.x - off] : 0;
        __syncthreads();
        s[threadIdx.x] += t;
        __syncthreads();
    }
    if (i < n) tmp[i] = s[threadIdx.x];
    if (threadIdx.x == 255) bsum[blockIdx.x] = s[255];
}

__global__ void k_scan2(int* __restrict__ bsum, int nb) {
    __shared__ int s[256];
    int v = (threadIdx.x < nb) ? bsum[threadIdx.x] : 0;
    s[threadIdx.x] = v;
    __syncthreads();
    for (int off = 1; off < 256; off <<= 1) {
        int t = (threadIdx.x >= off) ? s[threadIdx.x - off] : 0;
        __syncthreads();
        s[threadIdx.x] += t;
        __syncthreads();
    }
    if (threadIdx.x < nb) bsum[threadIdx.x] = s[threadIdx.x] - v; // exclusive
}

__global__ void k_scan3(const int* __restrict__ tmp, const int* __restrict__ cnt,
                        const int* __restrict__ bsum, int* __restrict__ row_start, int n) {
    int i = blockIdx.x * 256 + threadIdx.x;
    if (i < n) row_start[i] = tmp[i] - cnt[i] + bsum[blockIdx.x];
}

// ---- edge pass: exp(leaky(alpha)), ae; pack 32B CSR record; NO atomics ----
__global__ void k_scatter(const int* __restrict__ ei, const float* __restrict__ edge_attr,
                          const float* __restrict__ we_att, const float* __restrict__ a_src,
                          const float* __restrict__ a_dst, const int* __restrict__ row_start,
                          const int* __restrict__ rank, unsigned int* __restrict__ recp, int E) {
    __shared__ float wa[EDGE_DIM * HEADS];
    if (threadIdx.x < EDGE_DIM * HEADS) wa[threadIdx.x] = we_att[threadIdx.x];
    __syncthreads();
    int e = blockIdx.x * blockDim.x + threadIdx.x;
    if (e >= E) return;
    int s = ei[e], d = ei[E + e];
    const float4* ea4 = (const float4*)(edge_attr + (size_t)e * EDGE_DIM);
    float ae[HEADS] = {0.f, 0.f, 0.f, 0.f};
#pragma unroll
    for (int q = 0; q < 4; ++q) {
        float4 v4 = ea4[q];
        const float* vp = (const float*)&v4;
#pragma unroll
        for (int r = 0; r < 4; ++r) {
            float v = vp[r];
            int dd = q * 4 + r;
#pragma unroll
            for (int h = 0; h < HEADS; ++h) ae[h] += v * wa[dd * HEADS + h];
        }
    }
    float4 as4 = *(const float4*)(a_src + (size_t)s * HEADS);
    float4 ad4 = *(const float4*)(a_dst + (size_t)d * HEADS);
    const float* asp = (const float*)&as4;
    const float* adp = (const float*)&ad4;
    float ea[HEADS];
#pragma unroll
    for (int h = 0; h < HEADS; ++h) {
        float al = asp[h] + adp[h] + ae[h];
        al = al >= 0.0f ? al : NEG_SLOPE * al;
        ea[h] = __expf(al);          // no max-subtraction needed: |al| < ~8
    }
    int pos = row_start[d] + rank[e];
    size_t off = (size_t)pos * 8;
    uint4 w0;
    w0.x = (unsigned int)s;
    w0.y = pack_bf2(ea[0], ea[1]);
    w0.z = pack_bf2(ea[2], ea[3]);
    w0.w = pack_bf2(ae[0], ae[1]);
    *(uint4*)(recp + off) = w0;
    recp[off + 4] = pack_bf2(ae[2], ae[3]);
}

// ------- fused gather + softmax + aggregate + epilogue: 4 nodes/block, wave/node -------
#define PROC(A, B, R)                                                     \
    {                                                                     \
        unsigned ew = (h4 & 2) ? (A).z : (A).y;                           \
        unsigned aw = (h4 & 2) ? (B) : (A).w;                             \
        float a = (h4 & 1) ? bfhi(ew) : bflo(ew);                         \
        float ae = (h4 & 1) ? bfhi(aw) : bflo(aw);                        \
        dn += a; aeS += ae;                                               \
        acc0 += a * bfu((R).x); acc1 += a * bfu((R).y);                   \
        acc2 += a * bfu((R).z); acc3 += a * bfu((R).w);                   \
    }

__global__ void __launch_bounds__(256)
k_gather_out(const int* __restrict__ row_start, const int* __restrict__ cnt,
             const unsigned int* __restrict__ recp,
             const float* __restrict__ a_src, const float* __restrict__ a_dst,
             const __hip_bfloat16* __restrict__ xwb, const float* __restrict__ x,
             const float* __restrict__ bias, const unsigned short* __restrict__ WpB,
             const float* __restrict__ bp, const float* __restrict__ gamma,
             const float* __restrict__ beta, float* __restrict__ out, int n) {
    int tid = threadIdx.x, lane = tid & 63, wv = tid >> 6;
    int node = blockIdx.x * 4 + wv;
    bool valid = node < n;
    int nodeC = valid ? node : n - 1;
    int h4 = lane >> 4;

    __shared__ float gT[HC][4];      // [channel][node-in-block]
    __shared__ float psf[4][4][64];  // [nn][part][k]

    const unsigned short* xwu = (const unsigned short*)xwb;

    int rs = row_start[nodeC];
    int dg = valid ? cnt[nodeC] : 0;

    // hoisted self-node loads
    float as = a_src[nodeC * HEADS + h4];
    float ad = a_dst[nodeC * HEADS + h4];
    ushort4 sr = *(const ushort4*)(xwu + (size_t)nodeC * HC + (lane << 2));
    float4 bv = *(const float4*)(bias + (lane << 2));

    float acc0 = 0.f, acc1 = 0.f, acc2 = 0.f, acc3 = 0.f;
    float dn = 0.f, aeS = 0.f;

    const unsigned int* rp = recp + (size_t)rs * 8;
    int j = 0;
    for (; j + 4 <= dg; j += 4, rp += 32) {
        uint4 A0 = *(const uint4*)(rp);
        unsigned B0 = rp[4];
        uint4 A1 = *(const uint4*)(rp + 8);
        unsigned B1 = rp[12];
        uint4 A2 = *(const uint4*)(rp + 16);
        unsigned B2 = rp[20];
        uint4 A3 = *(const uint4*)(rp + 24);
        unsigned B3 = rp[28];
        ushort4 r0 = *(const ushort4*)(xwu + (size_t)A0.x * HC + (lane << 2));
        ushort4 r1 = *(const ushort4*)(xwu + (size_t)A1.x * HC + (lane << 2));
        ushort4 r2 = *(const ushort4*)(xwu + (size_t)A2.x * HC + (lane << 2));
        ushort4 r3 = *(const ushort4*)(xwu + (size_t)A3.x * HC + (lane << 2));
        PROC(A0, B0, r0)
        PROC(A1, B1, r1)
        PROC(A2, B2, r2)
        PROC(A3, B3, r3)
    }
    for (; j < dg; ++j, rp += 8) {
        uint4 A = *(const uint4*)(rp);
        unsigned B = rp[4];
        ushort4 r = *(const ushort4*)(xwu + (size_t)A.x * HC + (lane << 2));
        PROC(A, B, r)
    }

    // self-loop + normalize + bias; write to LDS
    float cf = fmaxf((float)dg, 1.0f);
    float al = as + ad + aeS / cf;
    al = al >= 0.f ? al : NEG_SLOPE * al;
    float el = __expf(al);
    float inv = 1.0f / (dn + el);
    int ch = lane << 2;
    gT[ch + 0][wv] = (acc0 + el * bfu(sr.x)) * inv + bv.x;
    gT[ch + 1][wv] = (acc1 + el * bfu(sr.y)) * inv + bv.y;
    gT[ch + 2][wv] = (acc2 + el * bfu(sr.z)) * inv + bv.z;
    gT[ch + 3][wv] = (acc3 + el * bfu(sr.w)) * inv + bv.w;
    __syncthreads();

    // projection: thread (part=wv, k=lane) does one quarter of the 256-dot for all 4 nodes
    int part = wv, k = lane;
    float p0 = 0.f, p1 = 0.f, p2 = 0.f, p3 = 0.f;
#pragma unroll 8
    for (int j2 = 0; j2 < 64; ++j2) {
        int jj = part * 64 + j2;
        float w = bfu(WpB[jj * EMB + k]);
        float4 gv = *(const float4*)&gT[jj][0];
        p0 += w * gv.x; p1 += w * gv.y; p2 += w * gv.z; p3 += w * gv.w;
    }
    psf[0][part][k] = p0;
    psf[1][part][k] = p1;
    psf[2][part][k] = p2;
    psf[3][part][k] = p3;
    __syncthreads();

    // final: wave wv handles its node; lane = channel k
    float p = psf[wv][0][lane] + psf[wv][1][lane] + psf[wv][2][lane] + psf[wv][3][lane] + bp[lane];
    float elv = p > 0.f ? p : expm1f(p);
    float xv = valid ? x[(size_t)node * EMB + lane] : 0.f;
    float hv = xv + elv;
    float s1 = hv, s2 = hv * hv;
    for (int off = 32; off > 0; off >>= 1) {
        s1 += __shfl_xor(s1, off);
        s2 += __shfl_xor(s2, off);
    }
    float mu = s1 * (1.0f / EMB);
    float var = s2 * (1.0f / EMB) - mu * mu;
    if (valid)
        out[(size_t)node * EMB + lane] = (hv - mu) * rsqrtf(var + LN_EPS) * gamma[lane] + beta[lane];
}

extern "C" void kernel_launch(void* const* d_in, const int* in_sizes, int n_in,
                              void* d_out, int out_size, void* d_ws, size_t ws_size,
                              hipStream_t stream) {
    const float* x        = (const float*)d_in[0];
    const int*   ei       = (const int*)d_in[1];
    const float* edge_attr= (const float*)d_in[2];
    const float* W        = (const float*)d_in[3];
    const float* W_edge   = (const float*)d_in[4];
    const float* att_src  = (const float*)d_in[5];
    const float* att_dst  = (const float*)d_in[6];
    const float* att_edge = (const float*)d_in[7];
    const float* bias     = (const float*)d_in[8];
    const float* Wp       = (const float*)d_in[9];
    const float* bp       = (const float*)d_in[10];
    const float* gamma    = (const float*)d_in[11];
    const float* beta     = (const float*)d_in[12];
    float* out = (float*)d_out;

    int n = in_sizes[0] / EMB;
    int E = in_sizes[1] / 2;
    int nb = (n + 255) / 256;

    float* ws = (float*)d_ws;
    float* a_src       = ws; ws += (size_t)n * HEADS;
    float* a_dst       = ws; ws += (size_t)n * HEADS;
    float* we_att      = ws; ws += EDGE_DIM * HEADS;
    __hip_bfloat16* xwb = (__hip_bfloat16*)ws; ws += (size_t)n * HC / 2;
    unsigned int* recp = (unsigned int*)ws; ws += (size_t)E * 8;    // 32B/edge
    unsigned short* WpB = (unsigned short*)ws; ws += HC * EMB / 2;
    unsigned short* WxT = (unsigned short*)ws; ws += NCOLS * EMB / 2;
    int* iw = (int*)ws;
    int* cnt       = iw; iw += n;
    int* rank      = iw; iw += E;
    int* row_start = iw; iw += n;
    int* tmp       = iw; iw += n;
    int* bsum      = iw; iw += 256;

    const int tb = 256;
    hipLaunchKernelGGL(k_init, dim3((n + tb - 1) / tb), dim3(tb), 0, stream, cnt, n);
    hipLaunchKernelGGL(k_prep, dim3((NCOLS * EMB + tb - 1) / tb), dim3(tb), 0, stream,
                       W_edge, att_edge, we_att, Wp, WpB, W, att_src, att_dst, WxT);
    hipLaunchKernelGGL(k_xw_mfma, dim3((n + 15) / 16), dim3(tb), 0, stream,
                       x, WxT, xwb, a_src, a_dst, n);
    hipLaunchKernelGGL(k_hist, dim3((E + tb - 1) / tb), dim3(tb), 0, stream, ei, cnt, rank, E);
    hipLaunchKernelGGL(k_scan1, dim3(nb), dim3(tb), 0, stream, cnt, tmp, bsum, n);
    hipLaunchKernelGGL(k_scan2, dim3(1), dim3(tb), 0, stream, bsum, nb);
    hipLaunchKernelGGL(k_scan3, dim3(nb), dim3(tb), 0, stream, tmp, cnt, bsum, row_start, n);
    hipLaunchKernelGGL(k_scatter, dim3((E + tb - 1) / tb), dim3(tb), 0, stream,
                       ei, edge_attr, we_att, a_src, a_dst, row_start, rank, recp, E);
    hipLaunchKernelGGL(k_gather_out, dim3((n + 3) / 4), dim3(tb), 0, stream,
                       row_start, cnt, recp, a_src, a_dst, xwb, x, bias, WpB, bp,
                       gamma, beta, out, n);
}